// Round 10
// baseline (69.039 us; speedup 1.0000x reference)
//
#include <hip/hip_runtime.h>
#include <hip/hip_fp16.h>

typedef __attribute__((ext_vector_type(8))) _Float16 half8;
typedef __attribute__((ext_vector_type(4))) float f32x4;

// DPP rotate-reduce within each 16-lane row: after ror 1,2,4,8 all 16 lanes
// hold the group sum. Validated numerically R6-R9.
template <int CTRL>
__device__ __forceinline__ float dpp_ror_add(float p) {
  int s = __builtin_amdgcn_update_dpp(0, __float_as_int(p), CTRL, 0xF, 0xF, true);
  return p + __int_as_float(s);
}

__device__ __forceinline__ unsigned int pack_f16x2(float a, float b) {
  __half2 h = __floats2half2_rn(a, b);  // .x (low) = a
  return *reinterpret_cast<unsigned int*>(&h);
}

// relu on 8 packed f16 via guaranteed v_pk_max_f16 (validated R9).
__device__ __forceinline__ half8 relu8(half8 v) {
  union { half8 h8; unsigned int u[4]; } a;
  a.h8 = v;
  unsigned int z = 0;
#pragma unroll
  for (int e = 0; e < 4; ++e)
    asm("v_pk_max_f16 %0, %1, %2" : "=v"(a.u[e]) : "v"(a.u[e]), "v"(z));
  return a.h8;
}

// ---------------------------------------------------------------------------
// Precompute (fp32 math, f16 outputs, packed as uint pairs):
//   hx2[512][128] uint = f16 pairs of x @ W1[:128]
//   hy2[512][128] uint = f16 pairs of y @ W1[128:] + b1
//   W2T2[n][128]  uint = f16 pairs of W2[k][n] (transposed)
// ---------------------------------------------------------------------------
__global__ void k_pre(const float* __restrict__ x, const float* __restrict__ y,
                      const float* __restrict__ W1, const float* __restrict__ b1,
                      const float* __restrict__ W2,
                      unsigned int* __restrict__ hx2, unsigned int* __restrict__ hy2,
                      unsigned int* __restrict__ W2T2) {
  const int b = blockIdx.x;
  const int t = threadIdx.x;
  if (b < 128) {
    const bool isx = (b < 64);
    const int i0 = (isx ? b : (b - 64)) * 8;
    const float* __restrict__ src = isx ? x : y;
    const float* __restrict__ W = W1 + (isx ? 0 : 128 * 256);
    float acc[8];
    const float binit = isx ? 0.0f : b1[t];
#pragma unroll
    for (int r = 0; r < 8; ++r) acc[r] = binit;
#pragma unroll 4
    for (int d = 0; d < 128; ++d) {
      const float wv = W[d * 256 + t];  // coalesced across t
#pragma unroll
      for (int r = 0; r < 8; ++r) acc[r] += src[(i0 + r) * 128 + d] * wv;  // uniform loads
    }
    unsigned int* __restrict__ dst = isx ? hx2 : hy2;
#pragma unroll
    for (int r = 0; r < 8; ++r) {
      const float o = __shfl_xor(acc[r], 1, 64);
      if (!(t & 1)) dst[(i0 + r) * 128 + (t >> 1)] = pack_f16x2(acc[r], o);
    }
  } else {
    const int n = b - 128;
    const float wv = W2[t * 256 + n];
    const float o = __shfl_xor(wv, 1, 64);
    if (!(t & 1)) W2T2[n * 128 + (t >> 1)] = pack_f16x2(wv, o);
  }
}

// ---------------------------------------------------------------------------
// Main fused kernel, v10 = R4 skeleton (best measured) + f16 A-gen +
// double-buffered A_lds (ONE barrier/g) + DPP epilogue (no part round-trip).
// Block = 256 thr (4 waves), grid = 512 (ig 0..63 x j-tile 0..7), 2 blocks/CU.
// Wave w: all 64 rows (mf=4), cols w*64..+63 (nf=4).
//   bq[8][4] half8 = 128 VGPR persistent B (sourceable from AGPR by MFMA).
// Per g, ONE barrier:
//   [tid<64: store g-1 from red[1-buf]] ->
//   K-loop on A[buf]: 8 kk x (4 ds_read_b128 + 16 MFMA f16), setprio whole loop ->
//   issue A-gen(g+1) loads (hx8 + 8x hy b128) ->
//   DPP epilogue: pr = sum_nf relu(acc+b2)*w3, 4x DPP ror, select tree,
//     1x 4B write to red[buf][w*68+row] (2-way banks) ->
//   A-pack(g+1) into A[buf^1]: pk_add + pk_max + 8 ds_write_b128 ->
//   __syncthreads().
// MFMA f16 frag layout (verified R1/R7+):
//   A: row=l15, k=8*l4+e ; B: col=l15, k=8*l4+e ; C: col=l15, row=4*l4+reg
// ---------------------------------------------------------------------------
__launch_bounds__(256, 2)
__global__ void k_main(const unsigned int* __restrict__ hx2,
                       const unsigned int* __restrict__ hy2,
                       const unsigned int* __restrict__ W2T2,
                       const float* __restrict__ b2, const float* __restrict__ W3,
                       const float* __restrict__ b3, float* __restrict__ out) {
  __shared__ __attribute__((aligned(16))) _Float16 A_lds[2][64 * 264];  // 67584 B
  __shared__ float red[2][4 * 68];                                      // 2176 B

  const int tid = threadIdx.x;
  const int lane = tid & 63;
  const int w = tid >> 6;        // wave 0..3 -> col slice w*64
  const int l15 = lane & 15;
  const int l4 = lane >> 4;
  const int ig = blockIdx.x >> 3;
  const int j0 = (blockIdx.x & 7) * 64;
  const int i0 = ig * 8;

  // ---- persistent B fragments: col = w*64+nf*16+l15, k = kk*32+l4*8 ----
  half8 bq[8][4];
  {
    const unsigned int* bb = W2T2 + (w * 64 + l15) * 128 + l4 * 4;
#pragma unroll
    for (int nf = 0; nf < 4; ++nf)
#pragma unroll
      for (int kk = 0; kk < 8; ++kk)
        bq[kk][nf] = *reinterpret_cast<const half8*>(bb + nf * 16 * 128 + kk * 16);
  }

  // ---- epilogue constants ----
  float b2v[4], w3v[4];
#pragma unroll
  for (int nf = 0; nf < 4; ++nf) {
    b2v[nf] = b2[w * 64 + nf * 16 + l15];
    w3v[nf] = W3[w * 64 + nf * 16 + l15];
  }
  const float b3v = b3[0];

  // ---- A-gen lane geometry: per b128 round, 2 rows (lane>>5), col (lane&31)*8
  const int rpar = lane >> 5;
  const int c32 = lane & 31;
  const unsigned int* __restrict__ hyb = hy2 + (j0 + w * 16 + rpar) * 128 + c32 * 4;
  const int arow0 = w * 16 + rpar;

  // ---- prologue: A-gen for g=0 into buffer 0 ----
  {
    const half8 xv = *reinterpret_cast<const half8*>(hx2 + i0 * 128 + c32 * 4);
    half8 hv[8];
#pragma unroll
    for (int c = 0; c < 8; ++c)
      hv[c] = *reinterpret_cast<const half8*>(hyb + c * 256);
#pragma unroll
    for (int c = 0; c < 8; ++c) {
      const half8 s = relu8(hv[c] + xv);
      *reinterpret_cast<half8*>(&A_lds[0][(arow0 + 2 * c) * 264 + c32 * 8]) = s;
    }
  }
  __syncthreads();

#pragma unroll 1
  for (int g = 0; g < 8; ++g) {
    const int buf = g & 1;
    const bool pre = (g < 7);

    // ---- store results of g-1 (red[1-buf] written before last barrier) ----
    if (g > 0 && tid < 64) {
      const float* rb = red[1 - buf];
      const float s = rb[0 * 68 + tid] + rb[1 * 68 + tid] +
                      rb[2 * 68 + tid] + rb[3 * 68 + tid] + b3v;
      out[(i0 + g - 1) * 512 + j0 + tid] = s;
    }

    // ---- K-loop: 32 ds_read_b128 + 128 MFMA on A[buf], no barriers ----
    f32x4 acc[4][4];
#pragma unroll
    for (int mf = 0; mf < 4; ++mf)
#pragma unroll
      for (int nf = 0; nf < 4; ++nf) acc[mf][nf] = (f32x4){0.f, 0.f, 0.f, 0.f};

    const _Float16* __restrict__ Ar = &A_lds[buf][0];
    __builtin_amdgcn_s_setprio(1);
#pragma unroll
    for (int kk = 0; kk < 8; ++kk) {
      half8 af[4];
#pragma unroll
      for (int mf = 0; mf < 4; ++mf)
        af[mf] = *reinterpret_cast<const half8*>(
            &Ar[(mf * 16 + l15) * 264 + kk * 32 + l4 * 8]);
#pragma unroll
      for (int mf = 0; mf < 4; ++mf)
#pragma unroll
        for (int nf = 0; nf < 4; ++nf)
          acc[mf][nf] = __builtin_amdgcn_mfma_f32_16x16x32_f16(
              af[mf], bq[kk][nf], acc[mf][nf], 0, 0, 0);
    }
    __builtin_amdgcn_s_setprio(0);

    // ---- issue A-gen(g+1) loads early (latency hides under DPP chain) ----
    half8 xv, hv0, hv1, hv2, hv3, hv4, hv5, hv6, hv7;
    if (pre) {
      xv  = *reinterpret_cast<const half8*>(hx2 + (i0 + g + 1) * 128 + c32 * 4);
      hv0 = *reinterpret_cast<const half8*>(hyb + 0 * 256);
      hv1 = *reinterpret_cast<const half8*>(hyb + 1 * 256);
      hv2 = *reinterpret_cast<const half8*>(hyb + 2 * 256);
      hv3 = *reinterpret_cast<const half8*>(hyb + 3 * 256);
      hv4 = *reinterpret_cast<const half8*>(hyb + 4 * 256);
      hv5 = *reinterpret_cast<const half8*>(hyb + 5 * 256);
      hv6 = *reinterpret_cast<const half8*>(hyb + 6 * 256);
      hv7 = *reinterpret_cast<const half8*>(hyb + 7 * 256);
    }

    // ---- DPP epilogue: pr = sum_nf relu(acc+b2)*w3, 16-lane ror-reduce ----
    float pr[4][4];
#pragma unroll
    for (int mf = 0; mf < 4; ++mf)
#pragma unroll
      for (int reg = 0; reg < 4; ++reg) {
        float p = 0.f;
#pragma unroll
        for (int nf = 0; nf < 4; ++nf)
          p += fmaxf(acc[mf][nf][reg] + b2v[nf], 0.f) * w3v[nf];
        p = dpp_ror_add<0x121>(p);
        p = dpp_ror_add<0x122>(p);
        p = dpp_ror_add<0x124>(p);
        p = dpp_ror_add<0x128>(p);
        pr[mf][reg] = p;
      }
    // select tree (validated R7): lane takes pr[l15>>2][l15&3]
    {
      const float a0 = (l15 & 1) ? pr[0][1] : pr[0][0];
      const float a1 = (l15 & 1) ? pr[0][3] : pr[0][2];
      const float a2 = (l15 & 1) ? pr[1][1] : pr[1][0];
      const float a3 = (l15 & 1) ? pr[1][3] : pr[1][2];
      const float a4 = (l15 & 1) ? pr[2][1] : pr[2][0];
      const float a5 = (l15 & 1) ? pr[2][3] : pr[2][2];
      const float a6 = (l15 & 1) ? pr[3][1] : pr[3][0];
      const float a7 = (l15 & 1) ? pr[3][3] : pr[3][2];
      const float c0 = (l15 & 2) ? a1 : a0;
      const float c1 = (l15 & 2) ? a3 : a2;
      const float c2 = (l15 & 2) ? a5 : a4;
      const float c3 = (l15 & 2) ? a7 : a6;
      const float d0 = (l15 & 4) ? c1 : c0;
      const float d1 = (l15 & 4) ? c3 : c2;
      const float v = (l15 & 8) ? d1 : d0;
      const int row = (l15 >> 2) * 16 + l4 * 4 + (l15 & 3);
      red[buf][w * 68 + row] = v;  // 2-way banks max
    }

    // ---- A-pack(g+1) into A[buf^1] ----
    if (pre) {
      _Float16* __restrict__ Aw = &A_lds[1 - buf][arow0 * 264 + c32 * 8];
      half8 s;
      s = relu8(hv0 + xv); *reinterpret_cast<half8*>(&Aw[0 * 2 * 264]) = s;
      s = relu8(hv1 + xv); *reinterpret_cast<half8*>(&Aw[1 * 2 * 264]) = s;
      s = relu8(hv2 + xv); *reinterpret_cast<half8*>(&Aw[2 * 2 * 264]) = s;
      s = relu8(hv3 + xv); *reinterpret_cast<half8*>(&Aw[3 * 2 * 264]) = s;
      s = relu8(hv4 + xv); *reinterpret_cast<half8*>(&Aw[4 * 2 * 264]) = s;
      s = relu8(hv5 + xv); *reinterpret_cast<half8*>(&Aw[5 * 2 * 264]) = s;
      s = relu8(hv6 + xv); *reinterpret_cast<half8*>(&Aw[6 * 2 * 264]) = s;
      s = relu8(hv7 + xv); *reinterpret_cast<half8*>(&Aw[7 * 2 * 264]) = s;
    }

    __syncthreads();  // A(g+1) ready, red(g) ready, A(g) reads done
  }

  // ---- tail store for g = 7 (red[1]) ----
  if (tid < 64) {
    const float* rb = red[1];
    const float s = rb[0 * 68 + tid] + rb[1 * 68 + tid] +
                    rb[2 * 68 + tid] + rb[3 * 68 + tid] + b3v;
    out[(i0 + 7) * 512 + j0 + tid] = s;
  }
}

extern "C" void kernel_launch(void* const* d_in, const int* in_sizes, int n_in,
                              void* d_out, int out_size, void* d_ws, size_t ws_size,
                              hipStream_t stream) {
  const float* x  = (const float*)d_in[0];
  const float* y  = (const float*)d_in[1];
  const float* W1 = (const float*)d_in[2];
  const float* b1 = (const float*)d_in[3];
  const float* W2 = (const float*)d_in[4];
  const float* b2 = (const float*)d_in[5];
  const float* W3 = (const float*)d_in[6];
  const float* b3 = (const float*)d_in[7];
  float* out = (float*)d_out;

  char* ws = (char*)d_ws;
  unsigned int* hx2  = (unsigned int*)ws;              // 262144 B
  unsigned int* hy2  = (unsigned int*)(ws + 262144);   // 262144 B
  unsigned int* W2T2 = (unsigned int*)(ws + 524288);   // 131072 B

  k_pre<<<384, 256, 0, stream>>>(x, y, W1, b1, W2, hx2, hy2, W2T2);
  k_main<<<512, 256, 0, stream>>>(hx2, hy2, W2T2, b2, W3, b3, out);
}

// Round 11
// 47.968 us; speedup vs baseline: 1.4393x; 1.4393x over previous
//
#include <hip/hip_runtime.h>
#include <hip/hip_fp16.h>

typedef __attribute__((ext_vector_type(8))) _Float16 half8;
typedef __attribute__((ext_vector_type(4))) float f32x4;

// DPP rotate-reduce within each 16-lane row: after ror 1,2,4,8 all 16 lanes
// hold the group sum. Validated numerically R6-R10.
template <int CTRL>
__device__ __forceinline__ float dpp_ror_add(float p) {
  int s = __builtin_amdgcn_update_dpp(0, __float_as_int(p), CTRL, 0xF, 0xF, true);
  return p + __int_as_float(s);
}

__device__ __forceinline__ unsigned int pack_f16x2(float a, float b) {
  __half2 h = __floats2half2_rn(a, b);  // .x (low) = a
  return *reinterpret_cast<unsigned int*>(&h);
}

// relu on 8 packed f16 via guaranteed v_pk_max_f16 (validated R9/R10).
__device__ __forceinline__ half8 relu8(half8 v) {
  union { half8 h8; unsigned int u[4]; } a;
  a.h8 = v;
  unsigned int z = 0;
#pragma unroll
  for (int e = 0; e < 4; ++e)
    asm("v_pk_max_f16 %0, %1, %2" : "=v"(a.u[e]) : "v"(a.u[e]), "v"(z));
  return a.h8;
}

// ---------------------------------------------------------------------------
// Precompute (fp32 math, f16 outputs, packed as uint pairs):
//   hx2[512][128] uint = f16 pairs of x @ W1[:128]
//   hy2[512][128] uint = f16 pairs of y @ W1[128:] + b1
//   W2T2[n][128]  uint = f16 pairs of W2[k][n] (transposed)
// ---------------------------------------------------------------------------
__global__ void k_pre(const float* __restrict__ x, const float* __restrict__ y,
                      const float* __restrict__ W1, const float* __restrict__ b1,
                      const float* __restrict__ W2,
                      unsigned int* __restrict__ hx2, unsigned int* __restrict__ hy2,
                      unsigned int* __restrict__ W2T2) {
  const int b = blockIdx.x;
  const int t = threadIdx.x;
  if (b < 128) {
    const bool isx = (b < 64);
    const int i0 = (isx ? b : (b - 64)) * 8;
    const float* __restrict__ src = isx ? x : y;
    const float* __restrict__ W = W1 + (isx ? 0 : 128 * 256);
    float acc[8];
    const float binit = isx ? 0.0f : b1[t];
#pragma unroll
    for (int r = 0; r < 8; ++r) acc[r] = binit;
#pragma unroll 4
    for (int d = 0; d < 128; ++d) {
      const float wv = W[d * 256 + t];  // coalesced across t
#pragma unroll
      for (int r = 0; r < 8; ++r) acc[r] += src[(i0 + r) * 128 + d] * wv;  // uniform loads
    }
    unsigned int* __restrict__ dst = isx ? hx2 : hy2;
#pragma unroll
    for (int r = 0; r < 8; ++r) {
      const float o = __shfl_xor(acc[r], 1, 64);
      if (!(t & 1)) dst[(i0 + r) * 128 + (t >> 1)] = pack_f16x2(acc[r], o);
    }
  } else {
    const int n = b - 128;
    const float wv = W2[t * 256 + n];
    const float o = __shfl_xor(wv, 1, 64);
    if (!(t & 1)) W2T2[n * 128 + (t >> 1)] = pack_f16x2(wv, o);
  }
}

// ---------------------------------------------------------------------------
// Main fused kernel, v11 = R4 liveness discipline + f16 + 1 barrier/g + DPP.
// Block = 256 thr (4 waves), grid = 512 (ig 0..63 x j-tile 0..7), 2 blocks/CU
// (anti-phased: one block's K-loop covers the other's A-gen/epilogue).
// Wave w: all 64 rows (mf=4), cols w*64..+63 (nf=4).
//   bq[8][4] half8 = 128 VGPR persistent B.
// Per g, ONE barrier, strict liveness order (acc retired BEFORE A-gen loads):
//   [tid<64: store g-1 from red[1-buf]] ->
//   K-loop on A[buf]: 8 kk x (4 ds_read_b128 + 16 MFMA f16), setprio(1) ->
//   DPP epilogue: pr = sum_nf relu(acc+b2)*w3 (acc dies), 4x DPP ror,
//     select tree, 1x 4B write red[buf][w*68+row] ->
//   A-gen(g+1): load xv + 8x hy b128, pk_add+pk_max, 8 ds_write_b128 ->
//   __syncthreads().
// MFMA f16 frag layout (verified R1/R7+):
//   A: row=l15, k=8*l4+e ; B: col=l15, k=8*l4+e ; C: col=l15, row=4*l4+reg
// ---------------------------------------------------------------------------
__launch_bounds__(256, 2)
__global__ void k_main(const unsigned int* __restrict__ hx2,
                       const unsigned int* __restrict__ hy2,
                       const unsigned int* __restrict__ W2T2,
                       const float* __restrict__ b2, const float* __restrict__ W3,
                       const float* __restrict__ b3, float* __restrict__ out) {
  __shared__ __attribute__((aligned(16))) _Float16 A_lds[2][64 * 264];  // 67584 B
  __shared__ float red[2][4 * 68];                                      // 2176 B

  const int tid = threadIdx.x;
  const int lane = tid & 63;
  const int w = tid >> 6;        // wave 0..3 -> col slice w*64
  const int l15 = lane & 15;
  const int l4 = lane >> 4;
  const int ig = blockIdx.x >> 3;
  const int j0 = (blockIdx.x & 7) * 64;
  const int i0 = ig * 8;

  // ---- persistent B fragments: col = w*64+nf*16+l15, k = kk*32+l4*8 ----
  half8 bq[8][4];
  {
    const unsigned int* bb = W2T2 + (w * 64 + l15) * 128 + l4 * 4;
#pragma unroll
    for (int nf = 0; nf < 4; ++nf)
#pragma unroll
      for (int kk = 0; kk < 8; ++kk)
        bq[kk][nf] = *reinterpret_cast<const half8*>(bb + nf * 16 * 128 + kk * 16);
  }

  // ---- epilogue constants ----
  float b2v[4], w3v[4];
#pragma unroll
  for (int nf = 0; nf < 4; ++nf) {
    b2v[nf] = b2[w * 64 + nf * 16 + l15];
    w3v[nf] = W3[w * 64 + nf * 16 + l15];
  }
  const float b3v = b3[0];

  // ---- A-gen lane geometry: per b128 round, 2 rows (lane>>5), col (lane&31)*8
  const int rpar = lane >> 5;
  const int c32 = lane & 31;
  const unsigned int* __restrict__ hyb = hy2 + (j0 + w * 16 + rpar) * 128 + c32 * 4;
  const int arow0 = w * 16 + rpar;

  // ---- prologue: A-gen for g=0 into buffer 0 ----
  {
    const half8 xv = *reinterpret_cast<const half8*>(hx2 + i0 * 128 + c32 * 4);
    half8 hv[8];
#pragma unroll
    for (int c = 0; c < 8; ++c)
      hv[c] = *reinterpret_cast<const half8*>(hyb + c * 256);
#pragma unroll
    for (int c = 0; c < 8; ++c) {
      const half8 s = relu8(hv[c] + xv);
      *reinterpret_cast<half8*>(&A_lds[0][(arow0 + 2 * c) * 264 + c32 * 8]) = s;
    }
  }
  __syncthreads();

#pragma unroll 1
  for (int g = 0; g < 8; ++g) {
    const int buf = g & 1;
    const bool pre = (g < 7);

    // ---- store results of g-1 (red[1-buf] written before last barrier) ----
    if (g > 0 && tid < 64) {
      const float* rb = red[1 - buf];
      const float s = rb[0 * 68 + tid] + rb[1 * 68 + tid] +
                      rb[2 * 68 + tid] + rb[3 * 68 + tid] + b3v;
      out[(i0 + g - 1) * 512 + j0 + tid] = s;
    }

    // ---- K-loop: 32 ds_read_b128 + 128 MFMA on A[buf], no barriers ----
    f32x4 acc[4][4];
#pragma unroll
    for (int mf = 0; mf < 4; ++mf)
#pragma unroll
      for (int nf = 0; nf < 4; ++nf) acc[mf][nf] = (f32x4){0.f, 0.f, 0.f, 0.f};

    const _Float16* __restrict__ Ar = &A_lds[buf][0];
    __builtin_amdgcn_s_setprio(1);
#pragma unroll
    for (int kk = 0; kk < 8; ++kk) {
      half8 af[4];
#pragma unroll
      for (int mf = 0; mf < 4; ++mf)
        af[mf] = *reinterpret_cast<const half8*>(
            &Ar[(mf * 16 + l15) * 264 + kk * 32 + l4 * 8]);
#pragma unroll
      for (int mf = 0; mf < 4; ++mf)
#pragma unroll
        for (int nf = 0; nf < 4; ++nf)
          acc[mf][nf] = __builtin_amdgcn_mfma_f32_16x16x32_f16(
              af[mf], bq[kk][nf], acc[mf][nf], 0, 0, 0);
    }
    __builtin_amdgcn_s_setprio(0);

    // ---- DPP epilogue FIRST (retires acc before any A-gen state is live) ----
    float pr[4][4];
#pragma unroll
    for (int mf = 0; mf < 4; ++mf)
#pragma unroll
      for (int reg = 0; reg < 4; ++reg) {
        float p = 0.f;
#pragma unroll
        for (int nf = 0; nf < 4; ++nf)
          p += fmaxf(acc[mf][nf][reg] + b2v[nf], 0.f) * w3v[nf];
        p = dpp_ror_add<0x121>(p);
        p = dpp_ror_add<0x122>(p);
        p = dpp_ror_add<0x124>(p);
        p = dpp_ror_add<0x128>(p);
        pr[mf][reg] = p;
      }
    // select tree (validated R7+): lane takes pr[l15>>2][l15&3]
    {
      const float a0 = (l15 & 1) ? pr[0][1] : pr[0][0];
      const float a1 = (l15 & 1) ? pr[0][3] : pr[0][2];
      const float a2 = (l15 & 1) ? pr[1][1] : pr[1][0];
      const float a3 = (l15 & 1) ? pr[1][3] : pr[1][2];
      const float a4 = (l15 & 1) ? pr[2][1] : pr[2][0];
      const float a5 = (l15 & 1) ? pr[2][3] : pr[2][2];
      const float a6 = (l15 & 1) ? pr[3][1] : pr[3][0];
      const float a7 = (l15 & 1) ? pr[3][3] : pr[3][2];
      const float c0 = (l15 & 2) ? a1 : a0;
      const float c1 = (l15 & 2) ? a3 : a2;
      const float c2 = (l15 & 2) ? a5 : a4;
      const float c3 = (l15 & 2) ? a7 : a6;
      const float d0 = (l15 & 4) ? c1 : c0;
      const float d1 = (l15 & 4) ? c3 : c2;
      const float v = (l15 & 8) ? d1 : d0;
      const int row = (l15 >> 2) * 16 + l4 * 4 + (l15 & 3);
      red[buf][w * 68 + row] = v;  // 2-way banks max
    }

    // ---- A-gen(g+1): loads NOW (acc dead; latency covered by other block) ----
    if (pre) {
      const half8 xv = *reinterpret_cast<const half8*>(hx2 + (i0 + g + 1) * 128 + c32 * 4);
      half8 hv[8];
#pragma unroll
      for (int c = 0; c < 8; ++c)
        hv[c] = *reinterpret_cast<const half8*>(hyb + c * 256);
      _Float16* __restrict__ Aw = &A_lds[1 - buf][arow0 * 264 + c32 * 8];
#pragma unroll
      for (int c = 0; c < 8; ++c) {
        const half8 s = relu8(hv[c] + xv);
        *reinterpret_cast<half8*>(&Aw[c * 2 * 264]) = s;
      }
    }

    __syncthreads();  // A(g+1) ready, red(g) ready, A(g) reads done
  }

  // ---- tail store for g = 7 (red[1]) ----
  if (tid < 64) {
    const float* rb = red[1];
    const float s = rb[0 * 68 + tid] + rb[1 * 68 + tid] +
                    rb[2 * 68 + tid] + rb[3 * 68 + tid] + b3v;
    out[(i0 + 7) * 512 + j0 + tid] = s;
  }
}

extern "C" void kernel_launch(void* const* d_in, const int* in_sizes, int n_in,
                              void* d_out, int out_size, void* d_ws, size_t ws_size,
                              hipStream_t stream) {
  const float* x  = (const float*)d_in[0];
  const float* y  = (const float*)d_in[1];
  const float* W1 = (const float*)d_in[2];
  const float* b1 = (const float*)d_in[3];
  const float* W2 = (const float*)d_in[4];
  const float* b2 = (const float*)d_in[5];
  const float* W3 = (const float*)d_in[6];
  const float* b3 = (const float*)d_in[7];
  float* out = (float*)d_out;

  char* ws = (char*)d_ws;
  unsigned int* hx2  = (unsigned int*)ws;              // 262144 B
  unsigned int* hy2  = (unsigned int*)(ws + 262144);   // 262144 B
  unsigned int* W2T2 = (unsigned int*)(ws + 524288);   // 131072 B

  k_pre<<<384, 256, 0, stream>>>(x, y, W1, b1, W2, hx2, hy2, W2T2);
  k_main<<<512, 256, 0, stream>>>(hx2, hy2, W2T2, b2, W3, b3, out);
}